// Round 18
// baseline (425.719 us; speedup 1.0000x reference)
//
#include <hip/hip_runtime.h>
#include <hip/hip_bf16.h>
#include <stdint.h>
#include <stddef.h>

// Dims (fixed): B=4096 L=64 H=512 E=256 T=256 S=128 CT=259 R=4096 V=256 IN=1670
// x layout: [a_tm1(256) | p_t(768) | n_t(128) | ctx_env(259) | ctx_lc(259)] = 1670 pad 1696
#define XP 1696
#define KC 288   // CT=259 padded to 9*32

// --- ctx group schedule geometry (r6 sparse scheduler) ---
#define BIG_G   8192
#define TWO_G   4096
#define ONE_G   2048
#define N_GROUP (BIG_G + TWO_G + ONE_G)
#define N_SLOTI (N_GROUP * 4)

// --- fused-kernel work blocks: 192 gh-GEMM + 512 aux, interleaved every 21st block ---
#define NGH 192
#define NAUX 512
#define NWORK (NGH + NAUX)          // 704
#define FUSE_GRID (N_GROUP + NWORK) // 15040

// --- pre fused-kernel partition: [0,NSP) s_proj GEMM (2 tiles/block), then aux ---
#define NSP 64
#define NAUX2 448

typedef __attribute__((ext_vector_type(8))) short bf16x8;
typedef __attribute__((ext_vector_type(4))) float f32x4;

__device__ __forceinline__ unsigned short f32_bf16(float f) {
    union { float f; unsigned int u; } v; v.f = f;
    unsigned int r = v.u + 0x7FFFu + ((v.u >> 16) & 1u);
    return (unsigned short)(r >> 16);
}
__device__ __forceinline__ float bf16_f32(unsigned short u) {
    union { unsigned int u; float f; } v; v.u = ((unsigned int)u) << 16;
    return v.f;
}

// ---------------- pack: dst[n][k] = bf16(src[k][n]), k>=Ksrc -> 0 ----------------
__global__ void tpack_kernel(const float* __restrict__ src, unsigned short* __restrict__ dst,
                             int Ksrc, int Nsrc, int Kp, long total) {
    long idx = (long)blockIdx.x * blockDim.x + threadIdx.x;
    if (idx >= total) return;
    int k = (int)(idx / Nsrc);
    int n = (int)(idx - (long)k * Nsrc);
    float v = (k < Ksrc) ? src[(size_t)k * Nsrc + n] : 0.0f;
    dst[(size_t)n * Kp + k] = f32_bf16(v);
}

__global__ void cvt_kernel(const float* __restrict__ src, unsigned short* __restrict__ dst, int total) {
    int idx = blockIdx.x * blockDim.x + threadIdx.x;
    if (idx < total) dst[idx] = f32_bf16(src[idx]);
}

// ---------------- ctx schedule: init + build (r6 sparse 2-kernel) ----------------
__global__ void sinit_kernel(int* __restrict__ s) {
    int i = blockIdx.x * 256 + threadIdx.x;
    if (i < N_SLOTI) s[i] = -1;
    else if (i < N_SLOTI + 3) s[i] = 0;
}

__global__ void sched_kernel(const int* __restrict__ len_env, const int* __restrict__ len_lc,
                             int* __restrict__ slots) {
    int idx = blockIdx.x * blockDim.x + threadIdx.x;
    if (idx >= 8192) return;
    int b = idx >> 1, wh = idx & 1;
    int len = wh ? len_lc[b] : len_env[b];
    int m = (len + 15) >> 4;
    if (m == 0) m = 1;
    if (m > 4) m = 4;
    int* cursors = slots + N_SLOTI;
    int base;
    if (m >= 3)      { int p = atomicAdd(&cursors[0], 1); base = p * 4; }
    else if (m == 2) { int p = atomicAdd(&cursors[1], 1); base = BIG_G * 4 + (p >> 1) * 4 + (p & 1) * 2; }
    else             { int p = atomicAdd(&cursors[2], 1); base = (BIG_G + TWO_G) * 4 + (p >> 2) * 4 + (p & 3); }
    for (int k = 0; k < m; k++) slots[base + k] = idx * 4 + k;
}

// ---------------- generic GEMM (m97 structure, BK=32 — r6 exact) ----------------
template<int ACT, int OUT_BF16>
__global__ __launch_bounds__(256, 2)
void gemm_bt_kernel(const unsigned short* __restrict__ A,
                    const unsigned short* __restrict__ BT,
                    const float* __restrict__ bias,
                    void* __restrict__ Cout,
                    int M, int N, int K)
{
    __shared__ unsigned short a_lds[128 * 32];
    __shared__ unsigned short b_lds[128 * 32];
    const int tid  = threadIdx.x;
    const int lane = tid & 63;
    const int wave = tid >> 6;
    const int wm = wave >> 1, wn = wave & 1;
    const int row0 = blockIdx.y * 128;
    const int col0 = blockIdx.x * 128;

    f32x4 acc[4][4];
    #pragma unroll
    for (int i = 0; i < 4; i++)
        #pragma unroll
        for (int j = 0; j < 4; j++) acc[i][j] = (f32x4){0.f, 0.f, 0.f, 0.f};

    const int fr = lane & 15;
    const int kk = (lane >> 4) * 8;
    const int srow = (lane >> 2);
    const int scol = (lane & 3) * 8;

    for (int k0 = 0; k0 < K; k0 += 32) {
        __syncthreads();
        #pragma unroll
        for (int j = 0; j < 4; j++) {
            const int c = (wave & 1) * 4 + j;
            const unsigned short* gsrc;
            unsigned short* ldst;
            if (wave < 2) {
                gsrc = A  + (size_t)(row0 + c * 16 + srow) * K + k0 + scol;
                ldst = &a_lds[c * 512];
            } else {
                gsrc = BT + (size_t)(col0 + c * 16 + srow) * K + k0 + scol;
                ldst = &b_lds[c * 512];
            }
            __builtin_amdgcn_global_load_lds(
                (const __attribute__((address_space(1))) void*)gsrc,
                (__attribute__((address_space(3))) void*)ldst, 16, 0, 0);
        }
        __syncthreads();

        bf16x8 af[4], bf[4];
        #pragma unroll
        for (int mt = 0; mt < 4; mt++) af[mt] = *(const bf16x8*)&a_lds[(wm * 64 + mt * 16 + fr) * 32 + kk];
        #pragma unroll
        for (int nt = 0; nt < 4; nt++) bf[nt] = *(const bf16x8*)&b_lds[(wn * 64 + nt * 16 + fr) * 32 + kk];
        #pragma unroll
        for (int mt = 0; mt < 4; mt++)
            #pragma unroll
            for (int nt = 0; nt < 4; nt++)
                acc[mt][nt] = __builtin_amdgcn_mfma_f32_16x16x32_bf16(af[mt], bf[nt], acc[mt][nt], 0, 0, 0);
    }

    const int fq = lane >> 4;
    #pragma unroll
    for (int mt = 0; mt < 4; mt++)
        #pragma unroll
        for (int nt = 0; nt < 4; nt++) {
            int cg = col0 + wn * 64 + nt * 16 + fr;
            float bv = bias ? bias[cg] : 0.0f;
            #pragma unroll
            for (int i = 0; i < 4; i++) {
                int rg = row0 + wm * 64 + mt * 16 + fq * 4 + i;
                float v = acc[mt][nt][i] + bv;
                if (ACT == 1) v = tanhf(v);
                if (OUT_BF16) ((unsigned short*)Cout)[(size_t)rg * N + cg] = f32_bf16(v);
                else          ((float*)Cout)[(size_t)rg * N + cg] = v;
            }
        }
}

// ---------------- PRE-FUSED: s_proj GEMM + xasm + W1eT/WhhT packs (r17) ----------------
__global__ __launch_bounds__(512, 4)
void pre_fused_kernel(const unsigned short* __restrict__ s_b,
                      const unsigned short* __restrict__ W1sT,
                      const float* __restrict__ b1,
                      float* __restrict__ s_proj,
                      const float* __restrict__ a_tm1, const float* __restrict__ p_t,
                      const int* __restrict__ sym, const float* __restrict__ symtab,
                      unsigned short* __restrict__ x_out,
                      const float* __restrict__ W1,
                      unsigned short* __restrict__ W1eT,
                      const float* __restrict__ W_hh,
                      unsigned short* __restrict__ WhhT)
{
    __shared__ __attribute__((aligned(16))) char smem[32768];
    const int tid = threadIdx.x;
    const int lane = tid & 63;
    const int wave = tid >> 6;
    const int fr = lane & 15;
    const int fq = lane >> 4;

    if (blockIdx.x < NSP) {
        const int half = wave >> 2;
        const int w4 = wave & 3;
        const int wm = w4 >> 1, wn = w4 & 1;
        const int t = blockIdx.x * 2 + half;
        const int col0 = (t & 3) * 128;
        const int row0 = (t >> 2) * 128;
        unsigned short* a_lds = (unsigned short*)(smem + half * 16384);
        unsigned short* b_lds = a_lds + 4096;

        f32x4 acc[4][4];
        #pragma unroll
        for (int i = 0; i < 4; i++)
            #pragma unroll
            for (int j = 0; j < 4; j++) acc[i][j] = (f32x4){0.f, 0.f, 0.f, 0.f};

        const int kk = (lane >> 4) * 8;
        const int srow = (lane >> 2);
        const int scol = (lane & 3) * 8;
        const int K = 512;

        for (int k0 = 0; k0 < K; k0 += 32) {
            __syncthreads();
            #pragma unroll
            for (int j = 0; j < 4; j++) {
                const int c = (w4 & 1) * 4 + j;
                const unsigned short* gsrc;
                unsigned short* ldst;
                if (w4 < 2) {
                    gsrc = s_b  + (size_t)(row0 + c * 16 + srow) * K + k0 + scol;
                    ldst = &a_lds[c * 512];
                } else {
                    gsrc = W1sT + (size_t)(col0 + c * 16 + srow) * K + k0 + scol;
                    ldst = &b_lds[c * 512];
                }
                __builtin_amdgcn_global_load_lds(
                    (const __attribute__((address_space(1))) void*)gsrc,
                    (__attribute__((address_space(3))) void*)ldst, 16, 0, 0);
            }
            __syncthreads();

            bf16x8 af[4], bf[4];
            #pragma unroll
            for (int mt = 0; mt < 4; mt++) af[mt] = *(const bf16x8*)&a_lds[(wm * 64 + mt * 16 + fr) * 32 + kk];
            #pragma unroll
            for (int nt = 0; nt < 4; nt++) bf[nt] = *(const bf16x8*)&b_lds[(wn * 64 + nt * 16 + fr) * 32 + kk];
            #pragma unroll
            for (int mt = 0; mt < 4; mt++)
                #pragma unroll
                for (int nt = 0; nt < 4; nt++)
                    acc[mt][nt] = __builtin_amdgcn_mfma_f32_16x16x32_bf16(af[mt], bf[nt], acc[mt][nt], 0, 0, 0);
        }

        #pragma unroll
        for (int mt = 0; mt < 4; mt++)
            #pragma unroll
            for (int nt = 0; nt < 4; nt++) {
                int cg = col0 + wn * 64 + nt * 16 + fr;
                float bv = b1[cg];
                #pragma unroll
                for (int i = 0; i < 4; i++) {
                    int rg = row0 + wm * 64 + mt * 16 + fq * 4 + i;
                    s_proj[(size_t)rg * 512 + cg] = acc[mt][nt][i] + bv;
                }
            }
        return;
    }

    // aux: xasm + W1eT pack + WhhT pack (grid-stride)
    const long stride = (long)NAUX2 * 512;
    long base = (long)(blockIdx.x - NSP) * 512 + tid;
    for (long q = base; q < (long)4096 * XP; q += stride) {
        int b = (int)(q / XP), c = (int)(q - (long)b * XP);
        float v;
        if (c < 256)       v = a_tm1[(size_t)b * 256 + c];
        else if (c < 1024) v = p_t[(size_t)b * 768 + (c - 256)];
        else if (c < 1152) v = symtab[(size_t)sym[b] * 128 + (c - 1024)];
        else if (c < 1670) continue;
        else v = 0.0f;
        x_out[q] = f32_bf16(v);
    }
    for (long q = base; q < (long)512 * KC; q += stride) {
        int n = (int)(q / KC), k = (int)(q - (long)n * KC);
        float v = (k < 259) ? W1[(size_t)(512 + k) * 512 + n] : 0.0f;
        W1eT[q] = f32_bf16(v);
    }
    for (long q = base; q < (long)1536 * 512; q += stride) {
        int n = (int)(q >> 9), k = (int)(q & 511);
        WhhT[q] = f32_bf16(W_hh[(size_t)k * 1536 + n]);
    }
}

// ---------------- FUSED: interleaved {ctx | gh-GEMM | aux} blocks ----------------
// Every 21st blockIdx (while work remains) is a work block -> each CU co-hosts
// latency-bound ctx blocks with compute-dense gh blocks for true overlap.
__global__ __launch_bounds__(512, 4)
void ctx_fused_kernel(const float* __restrict__ emb_env, const float* __restrict__ emb_lc,
                      const int* __restrict__ len_env, const int* __restrict__ len_lc,
                      const float* __restrict__ s_proj,
                      const unsigned short* __restrict__ W1eT,
                      const float* __restrict__ W2, const float* __restrict__ b2,
                      const int* __restrict__ slots,
                      unsigned short* __restrict__ x_out,
                      const unsigned short* __restrict__ s_b,
                      const unsigned short* __restrict__ WhhT,
                      const float* __restrict__ b_hh,
                      float* __restrict__ gh,
                      const float* __restrict__ W_ih, unsigned short* __restrict__ WihT,
                      const float* __restrict__ Wd,   unsigned short* __restrict__ WdT,
                      const float* __restrict__ rule, unsigned short* __restrict__ ruleb)
{
    __shared__ __attribute__((aligned(16))) char smem[40192];
    const int tid = threadIdx.x;   // 0..511
    const int lane = tid & 63;
    const int wave = tid >> 6;
    const int fr = lane & 15;
    const int fq = lane >> 4;

    // interleave mapping: i%21==0 && i/21<NWORK -> work i/21; else ctx i - min(i/21+1, NWORK)
    const int i = blockIdx.x;
    const int q21 = i / 21;
    const bool is_work = ((i % 21) == 0) && (q21 < NWORK);

    if (is_work) {
        const int wid = q21;
        if (wid < NGH) {
            // ======== gh GEMM: 2 tiles of 128x128, 4 waves each, K=512 ========
            const int half = wave >> 2;
            const int w4 = wave & 3;
            const int wm = w4 >> 1, wn = w4 & 1;
            const int t = wid * 2 + half;
            const int col0 = (t % 12) * 128;
            const int row0 = (t / 12) * 128;
            unsigned short* a_lds = (unsigned short*)(smem + half * 16384);
            unsigned short* b_lds = a_lds + 4096;

            f32x4 acc[4][4];
            #pragma unroll
            for (int ii = 0; ii < 4; ii++)
                #pragma unroll
                for (int j = 0; j < 4; j++) acc[ii][j] = (f32x4){0.f, 0.f, 0.f, 0.f};

            const int kk = (lane >> 4) * 8;
            const int srow = (lane >> 2);
            const int scol = (lane & 3) * 8;
            const int K = 512;

            for (int k0 = 0; k0 < K; k0 += 32) {
                __syncthreads();
                #pragma unroll
                for (int j = 0; j < 4; j++) {
                    const int c = (w4 & 1) * 4 + j;
                    const unsigned short* gsrc;
                    unsigned short* ldst;
                    if (w4 < 2) {
                        gsrc = s_b  + (size_t)(row0 + c * 16 + srow) * K + k0 + scol;
                        ldst = &a_lds[c * 512];
                    } else {
                        gsrc = WhhT + (size_t)(col0 + c * 16 + srow) * K + k0 + scol;
                        ldst = &b_lds[c * 512];
                    }
                    __builtin_amdgcn_global_load_lds(
                        (const __attribute__((address_space(1))) void*)gsrc,
                        (__attribute__((address_space(3))) void*)ldst, 16, 0, 0);
                }
                __syncthreads();

                bf16x8 af[4], bf[4];
                #pragma unroll
                for (int mt = 0; mt < 4; mt++) af[mt] = *(const bf16x8*)&a_lds[(wm * 64 + mt * 16 + fr) * 32 + kk];
                #pragma unroll
                for (int nt = 0; nt < 4; nt++) bf[nt] = *(const bf16x8*)&b_lds[(wn * 64 + nt * 16 + fr) * 32 + kk];
                #pragma unroll
                for (int mt = 0; mt < 4; mt++)
                    #pragma unroll
                    for (int nt = 0; nt < 4; nt++)
                        acc[mt][nt] = __builtin_amdgcn_mfma_f32_16x16x32_bf16(af[mt], bf[nt], acc[mt][nt], 0, 0, 0);
            }

            #pragma unroll
            for (int mt = 0; mt < 4; mt++)
                #pragma unroll
                for (int nt = 0; nt < 4; nt++) {
                    int cg = col0 + wn * 64 + nt * 16 + fr;
                    float bv = b_hh[cg];
                    #pragma unroll
                    for (int ii = 0; ii < 4; ii++) {
                        int rg = row0 + wm * 64 + mt * 16 + fq * 4 + ii;
                        gh[(size_t)rg * 1536 + cg] = acc[mt][nt][ii] + bv;
                    }
                }
            return;
        }
        // ======== aux: WihT pack + WdT pack + ruleb cvt (grid-stride) ========
        const long stride = (long)NAUX * 512;
        long base = (long)(wid - NGH) * 512 + tid;
        for (long q = base; q < (long)XP * 1536; q += stride) {
            int k = (int)(q / 1536);
            int n = (int)(q - (long)k * 1536);
            float v = (k < 1670) ? W_ih[(size_t)k * 1536 + n] : 0.0f;
            WihT[(size_t)n * XP + k] = f32_bf16(v);
        }
        for (long q = base; q < (long)512 * 256; q += stride) {
            int k = (int)(q / 256);
            int n = (int)(q - (long)k * 256);
            WdT[(size_t)n * 512 + k] = f32_bf16(Wd[(size_t)k * 256 + n]);
        }
        for (long q = base; q < (long)4096 * 256; q += stride)
            ruleb[q] = f32_bf16(rule[q]);
        return;
    }

    // ======== ctx (r14 body verbatim, interleave-mapped g) ========
    const int g = i - (q21 + 1 < NWORK ? q21 + 1 : NWORK);
    const int4 dv = *reinterpret_cast<const int4*>(slots + (size_t)g * 4);
    if (dv.x < 0) return;
    int d[4] = {dv.x, dv.y, dv.z, dv.w};

    unsigned short (*emb_lds)[296] = (unsigned short(*)[296])smem;
    float (*partial_lds)[64] = (float(*)[64])(smem + 37888);
    float* w_lds = (float*)(smem + 37888 + 2048);

    const float b2v = b2[0];

    // ---- stage: 128 threads per slot ----
    {
        const int sl = tid >> 7;
        const int t  = tid & 127;
        const int ds = d[sl];
        int nrows = 0;
        const float* src = nullptr;
        if (ds >= 0) {
            int it = ds >> 2, tix = ds & 3;
            int b = it >> 1, wh = it & 1;
            int len = (wh ? len_lc : len_env)[b];
            nrows = len - tix * 16;
            if (nrows > 16) nrows = 16;
            if (nrows < 0) nrows = 0;
            src = (wh ? emb_lc : emb_env) + ((size_t)b * 64 + tix * 16) * 259;
        }
        for (int q = t; q < 16 * 37; q += 128) {
            int r = q / 37, c = 259 + (q - (q / 37) * 37);
            emb_lds[sl * 16 + r][c] = 0;
        }
        const int nf4 = (nrows * 259 + 3) >> 2;
        const float4* s4 = reinterpret_cast<const float4*>(src);
        float4 v[9];
        #pragma unroll
        for (int j = 0; j < 9; j++) {
            int q = t + j * 128;
            if (q < nf4) v[j] = s4[q];
        }
        #pragma unroll
        for (int j = 0; j < 9; j++) {
            int q = t + j * 128;
            if (q < nf4) {
                float fv[4] = {v[j].x, v[j].y, v[j].z, v[j].w};
                int e0 = q * 4;
                #pragma unroll
                for (int jj = 0; jj < 4; jj++) {
                    int e = e0 + jj;
                    int r = e / 259;
                    int c = e - r * 259;
                    emb_lds[sl * 16 + r][c] = f32_bf16(fv[jj]);
                }
            }
        }
    }
    __syncthreads();

    // ---- MFMA: 4 M-tiles x 4 n-tiles (n-slice 64/wave), K=288 ----
    f32x4 acc[4][4];
    #pragma unroll
    for (int ii = 0; ii < 4; ii++)
        #pragma unroll
        for (int j = 0; j < 4; j++) acc[ii][j] = (f32x4){0.f, 0.f, 0.f, 0.f};

    #pragma unroll
    for (int ks = 0; ks < 9; ks++) {
        bf16x8 bfr[4];
        #pragma unroll
        for (int nt = 0; nt < 4; nt++) {
            int n = wave * 64 + nt * 16 + fr;
            bfr[nt] = *(const bf16x8*)(W1eT + (size_t)n * KC + ks * 32 + fq * 8);
        }
        bf16x8 af[4];
        #pragma unroll
        for (int mt = 0; mt < 4; mt++)
            af[mt] = *(const bf16x8*)&emb_lds[mt * 16 + fr][ks * 32 + fq * 8];
        __builtin_amdgcn_s_setprio(1);
        #pragma unroll
        for (int nt = 0; nt < 4; nt++)
            #pragma unroll
            for (int mt = 0; mt < 4; mt++)
                acc[mt][nt] = __builtin_amdgcn_mfma_f32_16x16x32_bf16(af[mt], bfr[nt], acc[mt][nt], 0, 0, 0);
        __builtin_amdgcn_s_setprio(0);
    }

    // ---- epilogue: relu(acc + s_proj) * W2 -> per-row logit partials ----
    int bslot[4];
    #pragma unroll
    for (int mt = 0; mt < 4; mt++) bslot[mt] = d[mt] >= 0 ? (d[mt] >> 3) : -1;

    float wv[4];
    #pragma unroll
    for (int nt = 0; nt < 4; nt++) wv[nt] = W2[wave * 64 + nt * 16 + fr];

    float plog[4][4];
    #pragma unroll
    for (int mt = 0; mt < 4; mt++)
        #pragma unroll
        for (int ii = 0; ii < 4; ii++) plog[mt][ii] = 0.f;
    #pragma unroll
    for (int nt = 0; nt < 4; nt++) {
        int n = wave * 64 + nt * 16 + fr;
        #pragma unroll
        for (int mt = 0; mt < 4; mt++) {
            if (bslot[mt] < 0) continue;
            float sp = s_proj[(size_t)bslot[mt] * 512 + n];
            #pragma unroll
            for (int ii = 0; ii < 4; ii++) {
                float h = acc[mt][nt][ii] + sp;
                h = fmaxf(h, 0.f);
                plog[mt][ii] += h * wv[nt];
            }
        }
    }
    #pragma unroll
    for (int mt = 0; mt < 4; mt++) {
        if (bslot[mt] < 0) continue;
        #pragma unroll
        for (int ii = 0; ii < 4; ii++) {
            float v = plog[mt][ii];
            v += __shfl_xor(v, 1); v += __shfl_xor(v, 2);
            v += __shfl_xor(v, 4); v += __shfl_xor(v, 8);
            if (fr == 0) partial_lds[wave][mt * 16 + fq * 4 + ii] = v;
        }
    }
    __syncthreads();

    // ---- per-item softmax ----
    if (wave < 4) {
        int dh = d[wave];
        if (dh >= 0 && (dh & 3) == 0) {
            int it = dh >> 2;
            int b = it >> 1, wh = it & 1;
            int len = (wh ? len_lc : len_env)[b];
            int m = (len + 15) >> 4; if (m == 0) m = 1;
            float logit = -1e9f;
            if (lane < 16 * m && lane < len) {
                logit = b2v;
                #pragma unroll
                for (int w = 0; w < 8; w++) logit += partial_lds[w][wave * 16 + lane];
            }
            float mx = logit;
            #pragma unroll
            for (int off = 1; off < 64; off <<= 1) mx = fmaxf(mx, __shfl_xor(mx, off));
            float e = __expf(logit - mx);
            float s = e;
            #pragma unroll
            for (int off = 1; off < 64; off <<= 1) s += __shfl_xor(s, off);
            if (lane < 16 * m) w_lds[wave * 16 + lane] = e / s;
        }
    }
    __syncthreads();

    // ---- wsum per head item ----
    #pragma unroll
    for (int g4 = 0; g4 < 4; g4++) {
        int dh = d[g4];
        if (dh < 0 || (dh & 3) != 0) continue;
        int it = dh >> 2;
        int b = it >> 1, wh = it & 1;
        int len = (wh ? len_lc : len_env)[b];
        int xoff = wh ? 1411 : 1152;
        if (tid < 259) {
            const int c = tid;
            const int base = g4 * 16;
            float a0 = 0.f, a1 = 0.f, a2 = 0.f, a3 = 0.f;
            int l = 0;
            for (; l + 3 < len; l += 4) {
                a0 += w_lds[base + l]     * bf16_f32(emb_lds[base + l][c]);
                a1 += w_lds[base + l + 1] * bf16_f32(emb_lds[base + l + 1][c]);
                a2 += w_lds[base + l + 2] * bf16_f32(emb_lds[base + l + 2][c]);
                a3 += w_lds[base + l + 3] * bf16_f32(emb_lds[base + l + 3][c]);
            }
            for (; l < len; l++) a0 += w_lds[base + l] * bf16_f32(emb_lds[base + l][c]);
            x_out[(size_t)b * XP + xoff + c] = f32_bf16((a0 + a1) + (a2 + a3));
        }
    }
}

// ---------------- GRU pointwise ----------------
__global__ void gru_kernel(const float* __restrict__ gx, const float* __restrict__ gh,
                           const float* __restrict__ s, unsigned short* __restrict__ h_b) {
    int idx = blockIdx.x * blockDim.x + threadIdx.x;
    if (idx >= 4096 * 512) return;
    int b = idx >> 9, c = idx & 511;
    const float* gxb = gx + (size_t)b * 1536;
    const float* ghb = gh + (size_t)b * 1536;
    float xr = gxb[c], xz = gxb[c + 512], xn = gxb[c + 1024];
    float hr = ghb[c], hz = ghb[c + 512], hn = ghb[c + 1024];
    float r = 1.f / (1.f + __expf(-(xr + hr)));
    float z = 1.f / (1.f + __expf(-(xz + hz)));
    float n = tanhf(xn + r * hn);
    float h = (1.f - z) * n + z * s[idx];
    h_b[idx] = f32_bf16(h);
}

// ---------------- host ----------------
extern "C" void kernel_launch(void* const* d_in, const int* in_sizes, int n_in,
                              void* d_out, int out_size, void* d_ws, size_t ws_size,
                              hipStream_t stream) {
    const float* s_tm1   = (const float*)d_in[0];
    const float* a_tm1   = (const float*)d_in[1];
    const float* p_t     = (const float*)d_in[2];
    const int*   sym     = (const int*)d_in[3];
    const float* env_emb = (const float*)d_in[4];
    const int*   env_len = (const int*)d_in[5];
    const float* lc_emb  = (const float*)d_in[6];
    const int*   lc_len  = (const int*)d_in[7];
    const float* symtab  = (const float*)d_in[8];
    const float* W1      = (const float*)d_in[9];
    const float* b1      = (const float*)d_in[10];
    const float* W2      = (const float*)d_in[11];
    const float* b2      = (const float*)d_in[12];
    const float* W_ih    = (const float*)d_in[13];
    const float* W_hh    = (const float*)d_in[14];
    const float* b_ih    = (const float*)d_in[15];
    const float* b_hh    = (const float*)d_in[16];
    const float* Wd      = (const float*)d_in[17];
    const float* bd      = (const float*)d_in[18];
    const float* rule    = (const float*)d_in[19];

    // ws layout (~43 MB)
    char* w = (char*)d_ws;
    float* s_proj = (float*)w;              w += (size_t)4096 * 512 * 4;
    unsigned short* W1sT  = (unsigned short*)w; w += (size_t)512 * 512 * 2;
    unsigned short* W1eT  = (unsigned short*)w; w += (size_t)512 * KC * 2;
    unsigned short* WihT  = (unsigned short*)w; w += (size_t)1536 * XP * 2;
    unsigned short* WhhT  = (unsigned short*)w; w += (size_t)1536 * 512 * 2;
    unsigned short* WdT   = (unsigned short*)w; w += (size_t)256 * 512 * 2;
    unsigned short* ruleb = (unsigned short*)w; w += (size_t)4096 * 256 * 2;
    unsigned short* s_b   = (unsigned short*)w; w += (size_t)4096 * 512 * 2;
    unsigned short* x_b   = (unsigned short*)w; w += (size_t)4096 * XP * 2;
    unsigned short* h_b   = (unsigned short*)w; w += (size_t)4096 * 512 * 2;
    unsigned short* dec_b = (unsigned short*)w; w += (size_t)4096 * 256 * 2;
    int* slots = (int*)w;                   w += (size_t)(N_SLOTI + 8) * 4;

    // d_out doubles as scratch for gx/gh (consumed before final logits write)
    float* out_f = (float*)d_out;
    float* gx = out_f;                        // [4096][1536]
    float* gh = out_f + (size_t)4096 * 1536;  // [4096][1536]

    // --- schedule init/build ---
    sinit_kernel<<<(N_SLOTI + 3 + 255) / 256, 256, 0, stream>>>(slots);
    sched_kernel<<<32, 256, 0, stream>>>(env_len, lc_len, slots);

    // --- minimal serial pre-work ---
    tpack_kernel<<<(512 * 512 + 255) / 256, 256, 0, stream>>>(W1, W1sT, 512, 512, 512, (long)512 * 512);
    cvt_kernel<<<8192, 256, 0, stream>>>(s_tm1, s_b, 4096 * 512);

    // PRE-FUSED: s_proj GEMM + xasm + W1eT/WhhT packs
    pre_fused_kernel<<<NSP + NAUX2, 512, 0, stream>>>(
        s_b, W1sT, b1, s_proj,
        a_tm1, p_t, sym, symtab, x_b,
        W1, W1eT, W_hh, WhhT);

    // FUSED (interleaved): ctx + gh GEMM + WihT/WdT/ruleb packs
    ctx_fused_kernel<<<FUSE_GRID, 512, 0, stream>>>(
        env_emb, lc_emb, env_len, lc_len, s_proj, W1eT, W2, b2, slots, x_b,
        s_b, WhhT, b_hh, gh,
        W_ih, WihT, Wd, WdT, rule, ruleb);

    // gx = x @ W_ih + b_ih
    gemm_bt_kernel<0, 0><<<dim3(12, 32), 256, 0, stream>>>(x_b, WihT, b_ih, gx, 4096, 1536, XP);
    gru_kernel<<<8192, 256, 0, stream>>>(gx, gh, s_tm1, h_b);

    // dec = tanh(h @ Wd + bd)  (bf16 out)
    gemm_bt_kernel<1, 1><<<dim3(2, 32), 256, 0, stream>>>(h_b, WdT, bd, dec_b, 4096, 256, 512);

    // logits = dec @ rule^T  (overwrites all of d_out)
    gemm_bt_kernel<0, 0><<<dim3(32, 32), 256, 0, stream>>>(dec_b, ruleb, nullptr, out_f, 4096, 4096, 256);
}

// Round 19
// 418.789 us; speedup vs baseline: 1.0165x; 1.0165x over previous
//
#include <hip/hip_runtime.h>
#include <hip/hip_bf16.h>
#include <stdint.h>
#include <stddef.h>

// Dims (fixed): B=4096 L=64 H=512 E=256 T=256 S=128 CT=259 R=4096 V=256 IN=1670
// x layout: [a_tm1(256) | p_t(768) | n_t(128) | ctx_env(259) | ctx_lc(259)] = 1670 pad 1696
#define XP 1696
#define KC 288   // CT=259 padded to 9*32

// --- ctx group schedule geometry (r6 sparse scheduler) ---
#define BIG_G   8192
#define TWO_G   4096
#define ONE_G   2048
#define N_GROUP (BIG_G + TWO_G + ONE_G)
#define N_SLOTI (N_GROUP * 4)

// --- ctx fused-kernel partition: [0,NGH) gh-GEMM, [NGH,CTX_OFF) aux, then ctx ---
#define NGH 192
#define NAUX 512
#define CTX_OFF (NGH + NAUX)

// --- pre fused-kernel partition: [0,NSP) s_proj GEMM (2 tiles/block), then aux ---
#define NSP 64
#define NAUX2 448

typedef __attribute__((ext_vector_type(8))) short bf16x8;
typedef __attribute__((ext_vector_type(4))) float f32x4;

__device__ __forceinline__ unsigned short f32_bf16(float f) {
    union { float f; unsigned int u; } v; v.f = f;
    unsigned int r = v.u + 0x7FFFu + ((v.u >> 16) & 1u);
    return (unsigned short)(r >> 16);
}
__device__ __forceinline__ float bf16_f32(unsigned short u) {
    union { unsigned int u; float f; } v; v.u = ((unsigned int)u) << 16;
    return v.f;
}

// ---------------- prep0: W1sT pack + s_b cvt (fused, grid-stride) ----------------
__global__ void prep0_kernel(const float* __restrict__ W1, unsigned short* __restrict__ W1sT,
                             const float* __restrict__ s_tm1, unsigned short* __restrict__ s_b) {
    const long stride = (long)gridDim.x * 256;
    long base = (long)blockIdx.x * 256 + threadIdx.x;
    // W1sT: dst[n*512+k] = bf16(W1[k*512+n]), 512x512
    for (long q = base; q < (long)512 * 512; q += stride) {
        int n = (int)(q >> 9), k = (int)(q & 511);
        W1sT[q] = f32_bf16(W1[(size_t)k * 512 + n]);
    }
    // s_b cvt: 4096x512
    for (long q = base; q < (long)4096 * 512; q += stride)
        s_b[q] = f32_bf16(s_tm1[q]);
}

// ---------------- ctx schedule: init + build (r6 sparse 2-kernel) ----------------
__global__ void sinit_kernel(int* __restrict__ s) {
    int i = blockIdx.x * 256 + threadIdx.x;
    if (i < N_SLOTI) s[i] = -1;
    else if (i < N_SLOTI + 3) s[i] = 0;
}

__global__ void sched_kernel(const int* __restrict__ len_env, const int* __restrict__ len_lc,
                             int* __restrict__ slots) {
    int idx = blockIdx.x * blockDim.x + threadIdx.x;
    if (idx >= 8192) return;
    int b = idx >> 1, wh = idx & 1;
    int len = wh ? len_lc[b] : len_env[b];
    int m = (len + 15) >> 4;
    if (m == 0) m = 1;
    if (m > 4) m = 4;
    int* cursors = slots + N_SLOTI;
    int base;
    if (m >= 3)      { int p = atomicAdd(&cursors[0], 1); base = p * 4; }
    else if (m == 2) { int p = atomicAdd(&cursors[1], 1); base = BIG_G * 4 + (p >> 1) * 4 + (p & 1) * 2; }
    else             { int p = atomicAdd(&cursors[2], 1); base = (BIG_G + TWO_G) * 4 + (p >> 2) * 4 + (p & 3); }
    for (int k = 0; k < m; k++) slots[base + k] = idx * 4 + k;
}

// ---------------- generic GEMM (m97 structure, BK=32 — r6 exact) ----------------
template<int ACT, int OUT_BF16>
__global__ __launch_bounds__(256, 2)
void gemm_bt_kernel(const unsigned short* __restrict__ A,
                    const unsigned short* __restrict__ BT,
                    const float* __restrict__ bias,
                    void* __restrict__ Cout,
                    int M, int N, int K)
{
    __shared__ unsigned short a_lds[128 * 32];
    __shared__ unsigned short b_lds[128 * 32];
    const int tid  = threadIdx.x;
    const int lane = tid & 63;
    const int wave = tid >> 6;
    const int wm = wave >> 1, wn = wave & 1;
    const int row0 = blockIdx.y * 128;
    const int col0 = blockIdx.x * 128;

    f32x4 acc[4][4];
    #pragma unroll
    for (int i = 0; i < 4; i++)
        #pragma unroll
        for (int j = 0; j < 4; j++) acc[i][j] = (f32x4){0.f, 0.f, 0.f, 0.f};

    const int fr = lane & 15;
    const int kk = (lane >> 4) * 8;
    const int srow = (lane >> 2);
    const int scol = (lane & 3) * 8;

    for (int k0 = 0; k0 < K; k0 += 32) {
        __syncthreads();
        #pragma unroll
        for (int j = 0; j < 4; j++) {
            const int c = (wave & 1) * 4 + j;
            const unsigned short* gsrc;
            unsigned short* ldst;
            if (wave < 2) {
                gsrc = A  + (size_t)(row0 + c * 16 + srow) * K + k0 + scol;
                ldst = &a_lds[c * 512];
            } else {
                gsrc = BT + (size_t)(col0 + c * 16 + srow) * K + k0 + scol;
                ldst = &b_lds[c * 512];
            }
            __builtin_amdgcn_global_load_lds(
                (const __attribute__((address_space(1))) void*)gsrc,
                (__attribute__((address_space(3))) void*)ldst, 16, 0, 0);
        }
        __syncthreads();

        bf16x8 af[4], bf[4];
        #pragma unroll
        for (int mt = 0; mt < 4; mt++) af[mt] = *(const bf16x8*)&a_lds[(wm * 64 + mt * 16 + fr) * 32 + kk];
        #pragma unroll
        for (int nt = 0; nt < 4; nt++) bf[nt] = *(const bf16x8*)&b_lds[(wn * 64 + nt * 16 + fr) * 32 + kk];
        #pragma unroll
        for (int mt = 0; mt < 4; mt++)
            #pragma unroll
            for (int nt = 0; nt < 4; nt++)
                acc[mt][nt] = __builtin_amdgcn_mfma_f32_16x16x32_bf16(af[mt], bf[nt], acc[mt][nt], 0, 0, 0);
    }

    const int fq = lane >> 4;
    #pragma unroll
    for (int mt = 0; mt < 4; mt++)
        #pragma unroll
        for (int nt = 0; nt < 4; nt++) {
            int cg = col0 + wn * 64 + nt * 16 + fr;
            float bv = bias ? bias[cg] : 0.0f;
            #pragma unroll
            for (int i = 0; i < 4; i++) {
                int rg = row0 + wm * 64 + mt * 16 + fq * 4 + i;
                float v = acc[mt][nt][i] + bv;
                if (ACT == 1) v = tanhf(v);
                if (OUT_BF16) ((unsigned short*)Cout)[(size_t)rg * N + cg] = f32_bf16(v);
                else          ((float*)Cout)[(size_t)rg * N + cg] = v;
            }
        }
}

// ---------------- PRE-FUSED: s_proj GEMM + xasm + W1eT/WhhT packs (r17 exact) ----------------
__global__ __launch_bounds__(512, 4)
void pre_fused_kernel(const unsigned short* __restrict__ s_b,
                      const unsigned short* __restrict__ W1sT,
                      const float* __restrict__ b1,
                      float* __restrict__ s_proj,
                      const float* __restrict__ a_tm1, const float* __restrict__ p_t,
                      const int* __restrict__ sym, const float* __restrict__ symtab,
                      unsigned short* __restrict__ x_out,
                      const float* __restrict__ W1,
                      unsigned short* __restrict__ W1eT,
                      const float* __restrict__ W_hh,
                      unsigned short* __restrict__ WhhT)
{
    __shared__ __attribute__((aligned(16))) char smem[32768];
    const int tid = threadIdx.x;
    const int lane = tid & 63;
    const int wave = tid >> 6;
    const int fr = lane & 15;
    const int fq = lane >> 4;

    if (blockIdx.x < NSP) {
        const int half = wave >> 2;
        const int w4 = wave & 3;
        const int wm = w4 >> 1, wn = w4 & 1;
        const int t = blockIdx.x * 2 + half;
        const int col0 = (t & 3) * 128;
        const int row0 = (t >> 2) * 128;
        unsigned short* a_lds = (unsigned short*)(smem + half * 16384);
        unsigned short* b_lds = a_lds + 4096;

        f32x4 acc[4][4];
        #pragma unroll
        for (int i = 0; i < 4; i++)
            #pragma unroll
            for (int j = 0; j < 4; j++) acc[i][j] = (f32x4){0.f, 0.f, 0.f, 0.f};

        const int kk = (lane >> 4) * 8;
        const int srow = (lane >> 2);
        const int scol = (lane & 3) * 8;
        const int K = 512;

        for (int k0 = 0; k0 < K; k0 += 32) {
            __syncthreads();
            #pragma unroll
            for (int j = 0; j < 4; j++) {
                const int c = (w4 & 1) * 4 + j;
                const unsigned short* gsrc;
                unsigned short* ldst;
                if (w4 < 2) {
                    gsrc = s_b  + (size_t)(row0 + c * 16 + srow) * K + k0 + scol;
                    ldst = &a_lds[c * 512];
                } else {
                    gsrc = W1sT + (size_t)(col0 + c * 16 + srow) * K + k0 + scol;
                    ldst = &b_lds[c * 512];
                }
                __builtin_amdgcn_global_load_lds(
                    (const __attribute__((address_space(1))) void*)gsrc,
                    (__attribute__((address_space(3))) void*)ldst, 16, 0, 0);
            }
            __syncthreads();

            bf16x8 af[4], bf[4];
            #pragma unroll
            for (int mt = 0; mt < 4; mt++) af[mt] = *(const bf16x8*)&a_lds[(wm * 64 + mt * 16 + fr) * 32 + kk];
            #pragma unroll
            for (int nt = 0; nt < 4; nt++) bf[nt] = *(const bf16x8*)&b_lds[(wn * 64 + nt * 16 + fr) * 32 + kk];
            #pragma unroll
            for (int mt = 0; mt < 4; mt++)
                #pragma unroll
                for (int nt = 0; nt < 4; nt++)
                    acc[mt][nt] = __builtin_amdgcn_mfma_f32_16x16x32_bf16(af[mt], bf[nt], acc[mt][nt], 0, 0, 0);
        }

        #pragma unroll
        for (int mt = 0; mt < 4; mt++)
            #pragma unroll
            for (int nt = 0; nt < 4; nt++) {
                int cg = col0 + wn * 64 + nt * 16 + fr;
                float bv = b1[cg];
                #pragma unroll
                for (int i = 0; i < 4; i++) {
                    int rg = row0 + wm * 64 + mt * 16 + fq * 4 + i;
                    s_proj[(size_t)rg * 512 + cg] = acc[mt][nt][i] + bv;
                }
            }
        return;
    }

    // aux: xasm + W1eT pack + WhhT pack (grid-stride)
    const long stride = (long)NAUX2 * 512;
    long base = (long)(blockIdx.x - NSP) * 512 + tid;
    for (long q = base; q < (long)4096 * XP; q += stride) {
        int b = (int)(q / XP), c = (int)(q - (long)b * XP);
        float v;
        if (c < 256)       v = a_tm1[(size_t)b * 256 + c];
        else if (c < 1024) v = p_t[(size_t)b * 768 + (c - 256)];
        else if (c < 1152) v = symtab[(size_t)sym[b] * 128 + (c - 1024)];
        else if (c < 1670) continue;
        else v = 0.0f;
        x_out[q] = f32_bf16(v);
    }
    for (long q = base; q < (long)512 * KC; q += stride) {
        int n = (int)(q / KC), k = (int)(q - (long)n * KC);
        float v = (k < 259) ? W1[(size_t)(512 + k) * 512 + n] : 0.0f;
        W1eT[q] = f32_bf16(v);
    }
    for (long q = base; q < (long)1536 * 512; q += stride) {
        int n = (int)(q >> 9), k = (int)(q & 511);
        WhhT[q] = f32_bf16(W_hh[(size_t)k * 1536 + n]);
    }
}

// ---------------- FUSED: gh-GEMM blocks + aux-pack blocks + ctx blocks (r17 exact) ----------------
__global__ __launch_bounds__(512, 4)
void ctx_fused_kernel(const float* __restrict__ emb_env, const float* __restrict__ emb_lc,
                      const int* __restrict__ len_env, const int* __restrict__ len_lc,
                      const float* __restrict__ s_proj,
                      const unsigned short* __restrict__ W1eT,
                      const float* __restrict__ W2, const float* __restrict__ b2,
                      const int* __restrict__ slots,
                      unsigned short* __restrict__ x_out,
                      const unsigned short* __restrict__ s_b,
                      const unsigned short* __restrict__ WhhT,
                      const float* __restrict__ b_hh,
                      float* __restrict__ gh,
                      const float* __restrict__ W_ih, unsigned short* __restrict__ WihT,
                      const float* __restrict__ Wd,   unsigned short* __restrict__ WdT,
                      const float* __restrict__ rule, unsigned short* __restrict__ ruleb)
{
    __shared__ __attribute__((aligned(16))) char smem[40192];
    const int tid = threadIdx.x;   // 0..511
    const int lane = tid & 63;
    const int wave = tid >> 6;
    const int fr = lane & 15;
    const int fq = lane >> 4;

    if (blockIdx.x < NGH) {
        // ======== gh GEMM: 2 tiles of 128x128, 4 waves each, K=512 ========
        const int half = wave >> 2;
        const int w4 = wave & 3;
        const int wm = w4 >> 1, wn = w4 & 1;
        const int t = blockIdx.x * 2 + half;
        const int col0 = (t % 12) * 128;
        const int row0 = (t / 12) * 128;
        unsigned short* a_lds = (unsigned short*)(smem + half * 16384);
        unsigned short* b_lds = a_lds + 4096;

        f32x4 acc[4][4];
        #pragma unroll
        for (int i = 0; i < 4; i++)
            #pragma unroll
            for (int j = 0; j < 4; j++) acc[i][j] = (f32x4){0.f, 0.f, 0.f, 0.f};

        const int kk = (lane >> 4) * 8;
        const int srow = (lane >> 2);
        const int scol = (lane & 3) * 8;
        const int K = 512;

        for (int k0 = 0; k0 < K; k0 += 32) {
            __syncthreads();
            #pragma unroll
            for (int j = 0; j < 4; j++) {
                const int c = (w4 & 1) * 4 + j;
                const unsigned short* gsrc;
                unsigned short* ldst;
                if (w4 < 2) {
                    gsrc = s_b  + (size_t)(row0 + c * 16 + srow) * K + k0 + scol;
                    ldst = &a_lds[c * 512];
                } else {
                    gsrc = WhhT + (size_t)(col0 + c * 16 + srow) * K + k0 + scol;
                    ldst = &b_lds[c * 512];
                }
                __builtin_amdgcn_global_load_lds(
                    (const __attribute__((address_space(1))) void*)gsrc,
                    (__attribute__((address_space(3))) void*)ldst, 16, 0, 0);
            }
            __syncthreads();

            bf16x8 af[4], bf[4];
            #pragma unroll
            for (int mt = 0; mt < 4; mt++) af[mt] = *(const bf16x8*)&a_lds[(wm * 64 + mt * 16 + fr) * 32 + kk];
            #pragma unroll
            for (int nt = 0; nt < 4; nt++) bf[nt] = *(const bf16x8*)&b_lds[(wn * 64 + nt * 16 + fr) * 32 + kk];
            #pragma unroll
            for (int mt = 0; mt < 4; mt++)
                #pragma unroll
                for (int nt = 0; nt < 4; nt++)
                    acc[mt][nt] = __builtin_amdgcn_mfma_f32_16x16x32_bf16(af[mt], bf[nt], acc[mt][nt], 0, 0, 0);
        }

        #pragma unroll
        for (int mt = 0; mt < 4; mt++)
            #pragma unroll
            for (int nt = 0; nt < 4; nt++) {
                int cg = col0 + wn * 64 + nt * 16 + fr;
                float bv = b_hh[cg];
                #pragma unroll
                for (int i = 0; i < 4; i++) {
                    int rg = row0 + wm * 64 + mt * 16 + fq * 4 + i;
                    gh[(size_t)rg * 1536 + cg] = acc[mt][nt][i] + bv;
                }
            }
        return;
    }

    if (blockIdx.x < CTX_OFF) {
        // ======== aux: WihT pack + WdT pack + ruleb cvt (grid-stride) ========
        const long stride = (long)NAUX * 512;
        long base = (long)(blockIdx.x - NGH) * 512 + tid;
        for (long q = base; q < (long)XP * 1536; q += stride) {
            int k = (int)(q / 1536);
            int n = (int)(q - (long)k * 1536);
            float v = (k < 1670) ? W_ih[(size_t)k * 1536 + n] : 0.0f;
            WihT[(size_t)n * XP + k] = f32_bf16(v);
        }
        for (long q = base; q < (long)512 * 256; q += stride) {
            int k = (int)(q / 256);
            int n = (int)(q - (long)k * 256);
            WdT[(size_t)n * 512 + k] = f32_bf16(Wd[(size_t)k * 256 + n]);
        }
        for (long q = base; q < (long)4096 * 256; q += stride)
            ruleb[q] = f32_bf16(rule[q]);
        return;
    }

    // ======== ctx (r14 body verbatim, g shifted) ========
    const int g = blockIdx.x - CTX_OFF;
    const int4 dv = *reinterpret_cast<const int4*>(slots + (size_t)g * 4);
    if (dv.x < 0) return;
    int d[4] = {dv.x, dv.y, dv.z, dv.w};

    unsigned short (*emb_lds)[296] = (unsigned short(*)[296])smem;
    float (*partial_lds)[64] = (float(*)[64])(smem + 37888);
    float* w_lds = (float*)(smem + 37888 + 2048);

    const float b2v = b2[0];

    // ---- stage: 128 threads per slot ----
    {
        const int sl = tid >> 7;
        const int t  = tid & 127;
        const int ds = d[sl];
        int nrows = 0;
        const float* src = nullptr;
        if (ds >= 0) {
            int it = ds >> 2, tix = ds & 3;
            int b = it >> 1, wh = it & 1;
            int len = (wh ? len_lc : len_env)[b];
            nrows = len - tix * 16;
            if (nrows > 16) nrows = 16;
            if (nrows < 0) nrows = 0;
            src = (wh ? emb_lc : emb_env) + ((size_t)b * 64 + tix * 16) * 259;
        }
        for (int q = t; q < 16 * 37; q += 128) {
            int r = q / 37, c = 259 + (q - (q / 37) * 37);
            emb_lds[sl * 16 + r][c] = 0;
        }
        const int nf4 = (nrows * 259 + 3) >> 2;
        const float4* s4 = reinterpret_cast<const float4*>(src);
        float4 v[9];
        #pragma unroll
        for (int j = 0; j < 9; j++) {
            int q = t + j * 128;
            if (q < nf4) v[j] = s4[q];
        }
        #pragma unroll
        for (int j = 0; j < 9; j++) {
            int q = t + j * 128;
            if (q < nf4) {
                float fv[4] = {v[j].x, v[j].y, v[j].z, v[j].w};
                int e0 = q * 4;
                #pragma unroll
                for (int jj = 0; jj < 4; jj++) {
                    int e = e0 + jj;
                    int r = e / 259;
                    int c = e - r * 259;
                    emb_lds[sl * 16 + r][c] = f32_bf16(fv[jj]);
                }
            }
        }
    }
    __syncthreads();

    // ---- MFMA: 4 M-tiles x 4 n-tiles (n-slice 64/wave), K=288 ----
    f32x4 acc[4][4];
    #pragma unroll
    for (int i = 0; i < 4; i++)
        #pragma unroll
        for (int j = 0; j < 4; j++) acc[i][j] = (f32x4){0.f, 0.f, 0.f, 0.f};

    #pragma unroll
    for (int ks = 0; ks < 9; ks++) {
        bf16x8 bfr[4];
        #pragma unroll
        for (int nt = 0; nt < 4; nt++) {
            int n = wave * 64 + nt * 16 + fr;
            bfr[nt] = *(const bf16x8*)(W1eT + (size_t)n * KC + ks * 32 + fq * 8);
        }
        bf16x8 af[4];
        #pragma unroll
        for (int mt = 0; mt < 4; mt++)
            af[mt] = *(const bf16x8*)&emb_lds[mt * 16 + fr][ks * 32 + fq * 8];
        __builtin_amdgcn_s_setprio(1);
        #pragma unroll
        for (int nt = 0; nt < 4; nt++)
            #pragma unroll
            for (int mt = 0; mt < 4; mt++)
                acc[mt][nt] = __builtin_amdgcn_mfma_f32_16x16x32_bf16(af[mt], bfr[nt], acc[mt][nt], 0, 0, 0);
        __builtin_amdgcn_s_setprio(0);
    }

    // ---- epilogue: relu(acc + s_proj) * W2 -> per-row logit partials ----
    int bslot[4];
    #pragma unroll
    for (int mt = 0; mt < 4; mt++) bslot[mt] = d[mt] >= 0 ? (d[mt] >> 3) : -1;

    float wv[4];
    #pragma unroll
    for (int nt = 0; nt < 4; nt++) wv[nt] = W2[wave * 64 + nt * 16 + fr];

    float plog[4][4];
    #pragma unroll
    for (int mt = 0; mt < 4; mt++)
        #pragma unroll
        for (int ii = 0; ii < 4; ii++) plog[mt][ii] = 0.f;
    #pragma unroll
    for (int nt = 0; nt < 4; nt++) {
        int n = wave * 64 + nt * 16 + fr;
        #pragma unroll
        for (int mt = 0; mt < 4; mt++) {
            if (bslot[mt] < 0) continue;
            float sp = s_proj[(size_t)bslot[mt] * 512 + n];
            #pragma unroll
            for (int ii = 0; ii < 4; ii++) {
                float h = acc[mt][nt][ii] + sp;
                h = fmaxf(h, 0.f);
                plog[mt][ii] += h * wv[nt];
            }
        }
    }
    #pragma unroll
    for (int mt = 0; mt < 4; mt++) {
        if (bslot[mt] < 0) continue;
        #pragma unroll
        for (int ii = 0; ii < 4; ii++) {
            float v = plog[mt][ii];
            v += __shfl_xor(v, 1); v += __shfl_xor(v, 2);
            v += __shfl_xor(v, 4); v += __shfl_xor(v, 8);
            if (fr == 0) partial_lds[wave][mt * 16 + fq * 4 + ii] = v;
        }
    }
    __syncthreads();

    // ---- per-item softmax ----
    if (wave < 4) {
        int dh = d[wave];
        if (dh >= 0 && (dh & 3) == 0) {
            int it = dh >> 2;
            int b = it >> 1, wh = it & 1;
            int len = (wh ? len_lc : len_env)[b];
            int m = (len + 15) >> 4; if (m == 0) m = 1;
            float logit = -1e9f;
            if (lane < 16 * m && lane < len) {
                logit = b2v;
                #pragma unroll
                for (int w = 0; w < 8; w++) logit += partial_lds[w][wave * 16 + lane];
            }
            float mx = logit;
            #pragma unroll
            for (int off = 1; off < 64; off <<= 1) mx = fmaxf(mx, __shfl_xor(mx, off));
            float e = __expf(logit - mx);
            float s = e;
            #pragma unroll
            for (int off = 1; off < 64; off <<= 1) s += __shfl_xor(s, off);
            if (lane < 16 * m) w_lds[wave * 16 + lane] = e / s;
        }
    }
    __syncthreads();

    // ---- wsum per head item ----
    #pragma unroll
    for (int g4 = 0; g4 < 4; g4++) {
        int dh = d[g4];
        if (dh < 0 || (dh & 3) != 0) continue;
        int it = dh >> 2;
        int b = it >> 1, wh = it & 1;
        int len = (wh ? len_lc : len_env)[b];
        int xoff = wh ? 1411 : 1152;
        if (tid < 259) {
            const int c = tid;
            const int base = g4 * 16;
            float a0 = 0.f, a1 = 0.f, a2 = 0.f, a3 = 0.f;
            int l = 0;
            for (; l + 3 < len; l += 4) {
                a0 += w_lds[base + l]     * bf16_f32(emb_lds[base + l][c]);
                a1 += w_lds[base + l + 1] * bf16_f32(emb_lds[base + l + 1][c]);
                a2 += w_lds[base + l + 2] * bf16_f32(emb_lds[base + l + 2][c]);
                a3 += w_lds[base + l + 3] * bf16_f32(emb_lds[base + l + 3][c]);
            }
            for (; l < len; l++) a0 += w_lds[base + l] * bf16_f32(emb_lds[base + l][c]);
            x_out[(size_t)b * XP + xoff + c] = f32_bf16((a0 + a1) + (a2 + a3));
        }
    }
}

// ---------------- GRU pointwise ----------------
__global__ void gru_kernel(const float* __restrict__ gx, const float* __restrict__ gh,
                           const float* __restrict__ s, unsigned short* __restrict__ h_b) {
    int idx = blockIdx.x * blockDim.x + threadIdx.x;
    if (idx >= 4096 * 512) return;
    int b = idx >> 9, c = idx & 511;
    const float* gxb = gx + (size_t)b * 1536;
    const float* ghb = gh + (size_t)b * 1536;
    float xr = gxb[c], xz = gxb[c + 512], xn = gxb[c + 1024];
    float hr = ghb[c], hz = ghb[c + 512], hn = ghb[c + 1024];
    float r = 1.f / (1.f + __expf(-(xr + hr)));
    float z = 1.f / (1.f + __expf(-(xz + hz)));
    float n = tanhf(xn + r * hn);
    float h = (1.f - z) * n + z * s[idx];
    h_b[idx] = f32_bf16(h);
}

// ---------------- host ----------------
extern "C" void kernel_launch(void* const* d_in, const int* in_sizes, int n_in,
                              void* d_out, int out_size, void* d_ws, size_t ws_size,
                              hipStream_t stream) {
    const float* s_tm1   = (const float*)d_in[0];
    const float* a_tm1   = (const float*)d_in[1];
    const float* p_t     = (const float*)d_in[2];
    const int*   sym     = (const int*)d_in[3];
    const float* env_emb = (const float*)d_in[4];
    const int*   env_len = (const int*)d_in[5];
    const float* lc_emb  = (const float*)d_in[6];
    const int*   lc_len  = (const int*)d_in[7];
    const float* symtab  = (const float*)d_in[8];
    const float* W1      = (const float*)d_in[9];
    const float* b1      = (const float*)d_in[10];
    const float* W2      = (const float*)d_in[11];
    const float* b2      = (const float*)d_in[12];
    const float* W_ih    = (const float*)d_in[13];
    const float* W_hh    = (const float*)d_in[14];
    const float* b_ih    = (const float*)d_in[15];
    const float* b_hh    = (const float*)d_in[16];
    const float* Wd      = (const float*)d_in[17];
    const float* bd      = (const float*)d_in[18];
    const float* rule    = (const float*)d_in[19];

    // ws layout (~43 MB)
    char* w = (char*)d_ws;
    float* s_proj = (float*)w;              w += (size_t)4096 * 512 * 4;
    unsigned short* W1sT  = (unsigned short*)w; w += (size_t)512 * 512 * 2;
    unsigned short* W1eT  = (unsigned short*)w; w += (size_t)512 * KC * 2;
    unsigned short* WihT  = (unsigned short*)w; w += (size_t)1536 * XP * 2;
    unsigned short* WhhT  = (unsigned short*)w; w += (size_t)1536 * 512 * 2;
    unsigned short* WdT   = (unsigned short*)w; w += (size_t)256 * 512 * 2;
    unsigned short* ruleb = (unsigned short*)w; w += (size_t)4096 * 256 * 2;
    unsigned short* s_b   = (unsigned short*)w; w += (size_t)4096 * 512 * 2;
    unsigned short* x_b   = (unsigned short*)w; w += (size_t)4096 * XP * 2;
    unsigned short* h_b   = (unsigned short*)w; w += (size_t)4096 * 512 * 2;
    unsigned short* dec_b = (unsigned short*)w; w += (size_t)4096 * 256 * 2;
    int* slots = (int*)w;                   w += (size_t)(N_SLOTI + 8) * 4;

    // d_out doubles as scratch for gx/gh (consumed before final logits write)
    float* out_f = (float*)d_out;
    float* gx = out_f;                        // [4096][1536]
    float* gh = out_f + (size_t)4096 * 1536;  // [4096][1536]

    // --- schedule init/build ---
    sinit_kernel<<<(N_SLOTI + 3 + 255) / 256, 256, 0, stream>>>(slots);
    sched_kernel<<<32, 256, 0, stream>>>(env_len, lc_len, slots);

    // --- minimal serial pre-work (fused W1sT pack + s_b cvt) ---
    prep0_kernel<<<2048, 256, 0, stream>>>(W1, W1sT, s_tm1, s_b);

    // PRE-FUSED: s_proj GEMM + xasm + W1eT/WhhT packs
    pre_fused_kernel<<<NSP + NAUX2, 512, 0, stream>>>(
        s_b, W1sT, b1, s_proj,
        a_tm1, p_t, sym, symtab, x_b,
        W1, W1eT, W_hh, WhhT);

    // FUSED: ctx + gh GEMM + WihT/WdT/ruleb packs
    ctx_fused_kernel<<<CTX_OFF + N_GROUP, 512, 0, stream>>>(
        env_emb, lc_emb, env_len, lc_len, s_proj, W1eT, W2, b2, slots, x_b,
        s_b, WhhT, b_hh, gh,
        W_ih, WihT, Wd, WdT, rule, ruleb);

    // gx = x @ W_ih + b_ih
    gemm_bt_kernel<0, 0><<<dim3(12, 32), 256, 0, stream>>>(x_b, WihT, b_ih, gx, 4096, 1536, XP);
    gru_kernel<<<8192, 256, 0, stream>>>(gx, gh, s_tm1, h_b);

    // dec = tanh(h @ Wd + bd)  (bf16 out)
    gemm_bt_kernel<1, 1><<<dim3(2, 32), 256, 0, stream>>>(h_b, WdT, bd, dec_b, 4096, 256, 512);

    // logits = dec @ rule^T  (overwrites all of d_out)
    gemm_bt_kernel<0, 0><<<dim3(32, 32), 256, 0, stream>>>(dec_b, ruleb, nullptr, out_f, 4096, 4096, 256);
}